// Round 1
// baseline (201.194 us; speedup 1.0000x reference)
//
#include <hip/hip_runtime.h>

typedef __attribute__((ext_vector_type(8))) short short8;
typedef __attribute__((ext_vector_type(4))) float f32x4;
typedef __attribute__((ext_vector_type(4))) unsigned short ushort4v;

#define BN_EPS 1e-5f
#define KOFF 27

static __device__ __forceinline__ unsigned short f2bf(float f) {
  unsigned int u = __float_as_uint(f);
  u += 0x7fffu + ((u >> 16) & 1u);
  return (unsigned short)(u >> 16);
}

static __device__ __forceinline__ float silu_f(float z) {
  return z / (1.f + __expf(-z));
}

// ---- BN affine vectors: s = g*rsqrt(v+eps), o = b - m*s (for both BNs)
__global__ void prep_bn(const float* __restrict__ g1, const float* __restrict__ b1,
                        const float* __restrict__ m1, const float* __restrict__ v1,
                        const float* __restrict__ g2, const float* __restrict__ b2,
                        const float* __restrict__ m2, const float* __restrict__ v2,
                        float* __restrict__ s1, float* __restrict__ o1,
                        float* __restrict__ s2, float* __restrict__ o2) {
  int c = threadIdx.x;
  if (c < 64) {
    float s = g1[c] * rsqrtf(v1[c] + BN_EPS);
    s1[c] = s; o1[c] = b1[c] - m1[c] * s;
    float q = g2[c] * rsqrtf(v2[c] + BN_EPS);
    s2[c] = q; o2[c] = b2[c] - m2[c] * q;
  }
}

// ---- time embedding MLP: tp = silu(t) @ Wt + bt; store (1+scale), shift
__global__ void time_mlp(const float* __restrict__ t, const float* __restrict__ Wt,
                         const float* __restrict__ bt,
                         float* __restrict__ scale_eff, float* __restrict__ shift) {
  int tid = blockIdx.x * blockDim.x + threadIdx.x; // 2048 = 16 batches * 128 out
  int bi = tid >> 7, co = tid & 127;
  float acc = bt[co];
  for (int e = 0; e < 256; ++e) {
    float tv = t[bi * 256 + e];
    acc += silu_f(tv) * Wt[e * 128 + co];
  }
  if (co < 64) scale_eff[bi * 64 + co] = 1.f + acc;
  else         shift[bi * 64 + (co - 64)] = acc;
}

// ---- pack W[k, ci, co] (f32) into bf16 MFMA B-fragment order.
// Fragment f = (k*2 + kk)*4 + cb holds B for k-half kk, col-block cb:
//   lane l, elem j  <-  W[k][kk*32 + (l>>4)*8 + j][cb*16 + (l&15)]
__global__ void pack_w(const float* __restrict__ W, unsigned short* __restrict__ Wp) {
  int tid = blockIdx.x * blockDim.x + threadIdx.x;
  if (tid >= KOFF * 2 * 4 * 64 * 8) return;
  int j = tid & 7, lane = (tid >> 3) & 63, cb = (tid >> 9) & 3, kk = (tid >> 11) & 1, k = tid >> 12;
  int ci = kk * 32 + (lane >> 4) * 8 + j;
  int co = cb * 16 + (lane & 15);
  Wp[tid] = f2bf(W[(k * 64 + ci) * 64 + co]);
}

// ---- a1 = bf16(silu(bn1(x)))
__global__ void bn_silu_k(const float* __restrict__ x, const float* __restrict__ s1,
                          const float* __restrict__ o1, unsigned short* __restrict__ out,
                          int total) {
  int i = (blockIdx.x * blockDim.x + threadIdx.x) * 4;
  if (i >= total) return;
  float4 v = *(const float4*)(x + i);
  int c = i & 63;
  float4 s = *(const float4*)(s1 + c);
  float4 o = *(const float4*)(o1 + c);
  ushort4v r;
  r.x = f2bf(silu_f(v.x * s.x + o.x));
  r.y = f2bf(silu_f(v.y * s.y + o.y));
  r.z = f2bf(silu_f(v.z * s.z + o.z));
  r.w = f2bf(silu_f(v.w * s.w + o.w));
  *(ushort4v*)(out + i) = r;
}

// ---- sparse conv tile kernel. 4 waves, tile = 64 nodes x 64 out-ch.
// Wave w owns nodes [n0+16w, n0+16w+16), all 64 out channels (4 cb frags).
// MODE 0: epilogue = +bias, FiLM(scale,shift via b[n]), bn2+silu -> bf16 a2
// MODE 1: epilogue = +bias + residual x -> f32 out
template <int MODE>
__global__ __launch_bounds__(256) void conv_k(
    const unsigned short* __restrict__ act, const int* __restrict__ idx,
    const int* __restrict__ valid, const unsigned short* __restrict__ Wp,
    const float* __restrict__ bias,
    const float* __restrict__ scale_eff, const float* __restrict__ shift,
    const int* __restrict__ bidx, const float* __restrict__ s2,
    const float* __restrict__ o2, const float* __restrict__ xres,
    unsigned short* __restrict__ out_bf, float* __restrict__ out_f, int N) {
  const int lane = threadIdx.x & 63;
  const int wid = threadIdx.x >> 6;
  const int row16 = lane & 15, grp = lane >> 4;
  const int n0 = blockIdx.x * 64;
  const int nA = n0 + wid * 16 + row16;
  const bool inA = nA < N;

  f32x4 acc0 = {0.f, 0.f, 0.f, 0.f};
  f32x4 acc1 = {0.f, 0.f, 0.f, 0.f};
  f32x4 acc2 = {0.f, 0.f, 0.f, 0.f};
  f32x4 acc3 = {0.f, 0.f, 0.f, 0.f};

  for (int k = 0; k < KOFF; ++k) {
    int v = 0, g = 0;
    if (inA) {
      v = valid[k * N + nA];
      g = idx[k * N + nA];
    }
    short8 a0 = {0, 0, 0, 0, 0, 0, 0, 0};
    short8 a1 = {0, 0, 0, 0, 0, 0, 0, 0};
    if (v) {
      const short8* rp = (const short8*)(act + (size_t)g * 64);
      a0 = rp[grp];       // k-half 0: elems grp*8 .. grp*8+7
      a1 = rp[grp + 4];   // k-half 1: elems 32+grp*8 ..
    }
    const short8* wp = (const short8*)Wp + ((size_t)k * 8) * 64 + lane;
    acc0 = __builtin_amdgcn_mfma_f32_16x16x32_bf16(a0, wp[0 * 64], acc0, 0, 0, 0);
    acc1 = __builtin_amdgcn_mfma_f32_16x16x32_bf16(a0, wp[1 * 64], acc1, 0, 0, 0);
    acc2 = __builtin_amdgcn_mfma_f32_16x16x32_bf16(a0, wp[2 * 64], acc2, 0, 0, 0);
    acc3 = __builtin_amdgcn_mfma_f32_16x16x32_bf16(a0, wp[3 * 64], acc3, 0, 0, 0);
    acc0 = __builtin_amdgcn_mfma_f32_16x16x32_bf16(a1, wp[4 * 64], acc0, 0, 0, 0);
    acc1 = __builtin_amdgcn_mfma_f32_16x16x32_bf16(a1, wp[5 * 64], acc1, 0, 0, 0);
    acc2 = __builtin_amdgcn_mfma_f32_16x16x32_bf16(a1, wp[6 * 64], acc2, 0, 0, 0);
    acc3 = __builtin_amdgcn_mfma_f32_16x16x32_bf16(a1, wp[7 * 64], acc3, 0, 0, 0);
  }

  // D frag: col = lane&15 (out-ch within cb), row = grp*4 + r (node within 16)
  if (MODE == 0) {
    int bi[4];
#pragma unroll
    for (int r = 0; r < 4; ++r) {
      int n = n0 + wid * 16 + grp * 4 + r;
      bi[r] = (n < N) ? bidx[n] : 0;
    }
#pragma unroll
    for (int cb = 0; cb < 4; ++cb) {
      f32x4 a = (cb == 0) ? acc0 : (cb == 1) ? acc1 : (cb == 2) ? acc2 : acc3;
      int c = cb * 16 + row16;
      float bb = bias[c], s2v = s2[c], o2v = o2[c];
#pragma unroll
      for (int r = 0; r < 4; ++r) {
        int n = n0 + wid * 16 + grp * 4 + r;
        if (n < N) {
          float h = a[r] + bb;
          h = scale_eff[bi[r] * 64 + c] * h + shift[bi[r] * 64 + c];
          float z = h * s2v + o2v;
          out_bf[(size_t)n * 64 + c] = f2bf(silu_f(z));
        }
      }
    }
  } else {
#pragma unroll
    for (int cb = 0; cb < 4; ++cb) {
      f32x4 a = (cb == 0) ? acc0 : (cb == 1) ? acc1 : (cb == 2) ? acc2 : acc3;
      int c = cb * 16 + row16;
      float bb = bias[c];
#pragma unroll
      for (int r = 0; r < 4; ++r) {
        int n = n0 + wid * 16 + grp * 4 + r;
        if (n < N) {
          out_f[(size_t)n * 64 + c] = a[r] + bb + xres[(size_t)n * 64 + c];
        }
      }
    }
  }
}

extern "C" void kernel_launch(void* const* d_in, const int* in_sizes, int n_in,
                              void* d_out, int out_size, void* d_ws, size_t ws_size,
                              hipStream_t stream) {
  const float* x    = (const float*)d_in[0];
  const float* t    = (const float*)d_in[1];
  const int*   b    = (const int*)d_in[2];
  const int*   kidx = (const int*)d_in[3];
  const int*   kval = (const int*)d_in[4];
  const float* bn1g = (const float*)d_in[5];
  const float* bn1b = (const float*)d_in[6];
  const float* bn1m = (const float*)d_in[7];
  const float* bn1v = (const float*)d_in[8];
  const float* W1   = (const float*)d_in[9];
  const float* b1c  = (const float*)d_in[10];
  const float* bn2g = (const float*)d_in[11];
  const float* bn2b = (const float*)d_in[12];
  const float* bn2m = (const float*)d_in[13];
  const float* bn2v = (const float*)d_in[14];
  const float* W2   = (const float*)d_in[15];
  const float* b2c  = (const float*)d_in[16];
  const float* Wt   = (const float*)d_in[17];
  const float* bt   = (const float*)d_in[18];
  float* out = (float*)d_out;

  const int N = in_sizes[2];        // 100000
  const int total = N * 64;

  // workspace layout (bytes)
  char* ws = (char*)d_ws;
  size_t actB = (size_t)total * 2;                 // 12.8 MB, 256-aligned
  unsigned short* a1bf = (unsigned short*)ws;
  unsigned short* a2bf = (unsigned short*)(ws + actB);
  const size_t wpackB = (size_t)KOFF * 2 * 4 * 64 * 8 * 2;  // 221184 B
  unsigned short* W1p = (unsigned short*)(ws + 2 * actB);
  unsigned short* W2p = (unsigned short*)(ws + 2 * actB + wpackB);
  float* scale_eff = (float*)(ws + 2 * actB + 2 * wpackB);
  float* shiftp    = scale_eff + 16 * 64;
  float* s1 = shiftp + 16 * 64;
  float* o1 = s1 + 64;
  float* s2 = s1 + 128;
  float* o2 = s1 + 192;

  prep_bn<<<1, 64, 0, stream>>>(bn1g, bn1b, bn1m, bn1v, bn2g, bn2b, bn2m, bn2v,
                                s1, o1, s2, o2);
  time_mlp<<<8, 256, 0, stream>>>(t, Wt, bt, scale_eff, shiftp);
  pack_w<<<(KOFF * 2 * 4 * 64 * 8 + 255) / 256, 256, 0, stream>>>(W1, W1p);
  pack_w<<<(KOFF * 2 * 4 * 64 * 8 + 255) / 256, 256, 0, stream>>>(W2, W2p);
  bn_silu_k<<<(total / 4 + 255) / 256, 256, 0, stream>>>(x, s1, o1, a1bf, total);

  int nblk = (N + 63) / 64;
  conv_k<0><<<nblk, 256, 0, stream>>>(a1bf, kidx, kval, W1p, b1c, scale_eff,
                                      shiftp, b, s2, o2, nullptr, a2bf, nullptr, N);
  conv_k<1><<<nblk, 256, 0, stream>>>(a2bf, kidx, kval, W2p, b2c, nullptr, nullptr,
                                      nullptr, nullptr, nullptr, x, nullptr, out, N);
}

// Round 2
// 191.430 us; speedup vs baseline: 1.0510x; 1.0510x over previous
//
#include <hip/hip_runtime.h>

typedef __attribute__((ext_vector_type(8))) short short8;
typedef __attribute__((ext_vector_type(16))) float f32x16;
typedef __attribute__((ext_vector_type(4))) unsigned short ushort4v;

#define BN_EPS 1e-5f
#define KOFF 27

static __device__ __forceinline__ unsigned short f2bf(float f) {
  unsigned int u = __float_as_uint(f);
  u += 0x7fffu + ((u >> 16) & 1u);
  return (unsigned short)(u >> 16);
}

static __device__ __forceinline__ float silu_f(float z) {
  return z / (1.f + __expf(-z));
}

// ---- BN affine vectors: s = g*rsqrt(v+eps), o = b - m*s (for both BNs)
__global__ void prep_bn(const float* __restrict__ g1, const float* __restrict__ b1,
                        const float* __restrict__ m1, const float* __restrict__ v1,
                        const float* __restrict__ g2, const float* __restrict__ b2,
                        const float* __restrict__ m2, const float* __restrict__ v2,
                        float* __restrict__ s1, float* __restrict__ o1,
                        float* __restrict__ s2, float* __restrict__ o2) {
  int c = threadIdx.x;
  if (c < 64) {
    float s = g1[c] * rsqrtf(v1[c] + BN_EPS);
    s1[c] = s; o1[c] = b1[c] - m1[c] * s;
    float q = g2[c] * rsqrtf(v2[c] + BN_EPS);
    s2[c] = q; o2[c] = b2[c] - m2[c] * q;
  }
}

// ---- time embedding MLP: tp = silu(t) @ Wt + bt; store (1+scale), shift
__global__ void time_mlp(const float* __restrict__ t, const float* __restrict__ Wt,
                         const float* __restrict__ bt,
                         float* __restrict__ scale_eff, float* __restrict__ shift) {
  int tid = blockIdx.x * blockDim.x + threadIdx.x; // 2048 = 16 batches * 128 out
  int bi = tid >> 7, co = tid & 127;
  float acc = bt[co];
  for (int e = 0; e < 256; ++e) {
    float tv = t[bi * 256 + e];
    acc += silu_f(tv) * Wt[e * 128 + co];
  }
  if (co < 64) scale_eff[bi * 64 + co] = 1.f + acc;
  else         shift[bi * 64 + (co - 64)] = acc;
}

// ---- pack W[k, ci, co] (f32) into bf16 MFMA B-fragment order for 32x32x16.
// Fragment f = (k*4 + ks)*2 + cb : lane l elem j <- W[k][ks*16 + (l>>5)*8 + j][cb*32 + (l&31)]
__global__ void pack_w32(const float* __restrict__ W, unsigned short* __restrict__ Wp) {
  int tid = blockIdx.x * blockDim.x + threadIdx.x;
  if (tid >= KOFF * 4 * 2 * 64 * 8) return;
  int j = tid & 7, lane = (tid >> 3) & 63, cb = (tid >> 9) & 1, ks = (tid >> 10) & 3, k = tid >> 12;
  int ci = ks * 16 + (lane >> 5) * 8 + j;
  int co = cb * 32 + (lane & 31);
  Wp[tid] = f2bf(W[(k * 64 + ci) * 64 + co]);
}

// ---- a1 = bf16(silu(bn1(x)))
__global__ void bn_silu_k(const float* __restrict__ x, const float* __restrict__ s1,
                          const float* __restrict__ o1, unsigned short* __restrict__ out,
                          int total) {
  int i = (blockIdx.x * blockDim.x + threadIdx.x) * 4;
  if (i >= total) return;
  float4 v = *(const float4*)(x + i);
  int c = i & 63;
  float4 s = *(const float4*)(s1 + c);
  float4 o = *(const float4*)(o1 + c);
  ushort4v r;
  r.x = f2bf(silu_f(v.x * s.x + o.x));
  r.y = f2bf(silu_f(v.y * s.y + o.y));
  r.z = f2bf(silu_f(v.z * s.z + o.z));
  r.w = f2bf(silu_f(v.w * s.w + o.w));
  *(ushort4v*)(out + i) = r;
}

// ---- sparse conv: 4 waves/block, 32 nodes per wave (32x32x16 MFMA), 128 nodes/block.
// MODE 0: epilogue = +bias, FiLM, bn2+silu -> bf16 a2
// MODE 1: epilogue = +bias + residual x -> f32 out
template <int MODE>
__global__ __launch_bounds__(256, 4) void conv_k(
    const unsigned short* __restrict__ act, const int* __restrict__ idx,
    const int* __restrict__ valid, const unsigned short* __restrict__ Wp,
    const float* __restrict__ bias,
    const float* __restrict__ scale_eff, const float* __restrict__ shift,
    const int* __restrict__ bidx, const float* __restrict__ s2,
    const float* __restrict__ o2, const float* __restrict__ xres,
    unsigned short* __restrict__ out_bf, float* __restrict__ out_f, int N) {
  const int lane = threadIdx.x & 63;
  const int wid = threadIdx.x >> 6;
  const int half = lane >> 5;     // 0/1
  const int r32 = lane & 31;
  const int n0w = blockIdx.x * 128 + wid * 32;
  const int nA = n0w + r32;
  const bool inA = nA < N;

  f32x16 acc0, acc1;
#pragma unroll
  for (int i = 0; i < 16; ++i) { acc0[i] = 0.f; acc1[i] = 0.f; }

  const short8 zero8 = {0, 0, 0, 0, 0, 0, 0, 0};
  short8 ab0[4], ab1[4];
  int vv0, gg0, vv1, gg1;

#define LOADVG(kk, v, g) do { \
    if ((kk) < KOFF && inA) { v = valid[(size_t)(kk) * N + nA]; g = idx[(size_t)(kk) * N + nA]; } \
    else { v = 0; g = 0; } } while (0)

#define GATHER(AB, v, g) do { \
    AB[0] = zero8; AB[1] = zero8; AB[2] = zero8; AB[3] = zero8; \
    if (v) { const short8* rp = (const short8*)(act + (size_t)(g) * 64); \
      AB[0] = rp[0 + half]; AB[1] = rp[2 + half]; AB[2] = rp[4 + half]; AB[3] = rp[6 + half]; } \
  } while (0)

#define DO_MFMA(AB) do { \
    acc0 = __builtin_amdgcn_mfma_f32_32x32x16_bf16(AB[0], wbase[0 * 128 + 0],  acc0, 0, 0, 0); \
    acc1 = __builtin_amdgcn_mfma_f32_32x32x16_bf16(AB[0], wbase[0 * 128 + 64], acc1, 0, 0, 0); \
    acc0 = __builtin_amdgcn_mfma_f32_32x32x16_bf16(AB[1], wbase[1 * 128 + 0],  acc0, 0, 0, 0); \
    acc1 = __builtin_amdgcn_mfma_f32_32x32x16_bf16(AB[1], wbase[1 * 128 + 64], acc1, 0, 0, 0); \
    acc0 = __builtin_amdgcn_mfma_f32_32x32x16_bf16(AB[2], wbase[2 * 128 + 0],  acc0, 0, 0, 0); \
    acc1 = __builtin_amdgcn_mfma_f32_32x32x16_bf16(AB[2], wbase[2 * 128 + 64], acc1, 0, 0, 0); \
    acc0 = __builtin_amdgcn_mfma_f32_32x32x16_bf16(AB[3], wbase[3 * 128 + 0],  acc0, 0, 0, 0); \
    acc1 = __builtin_amdgcn_mfma_f32_32x32x16_bf16(AB[3], wbase[3 * 128 + 64], acc1, 0, 0, 0); \
  } while (0)

  LOADVG(0, vv0, gg0);
  GATHER(ab0, vv0, gg0);
  LOADVG(1, vv1, gg1);

#pragma unroll
  for (int k = 0; k < KOFF; ++k) {
    // issue gather for k+1 early (its vg was loaded 2 iterations back)
    if (k + 1 < KOFF) {
      if (k & 1) { GATHER(ab0, vv0, gg0); } else { GATHER(ab1, vv1, gg1); }
    }
    // prefetch vg for k+2 into the slot whose gather was just consumed
    if (k & 1) { LOADVG(k + 2, vv1, gg1); } else { LOADVG(k + 2, vv0, gg0); }

    const short8* wbase = (const short8*)Wp + (size_t)k * 512 + lane;
    if (k & 1) { DO_MFMA(ab1); } else { DO_MFMA(ab0); }
  }

  // D frag: col = cb*32 + (lane&31), row = (r&3) + 8*(r>>2) + 4*half
  if (MODE == 0) {
#pragma unroll
    for (int cb = 0; cb < 2; ++cb) {
      f32x16 a = cb ? acc1 : acc0;
      int c = cb * 32 + r32;
      float bb = bias[c], s2v = s2[c], o2v = o2[c];
#pragma unroll
      for (int r = 0; r < 16; ++r) {
        int row = (r & 3) + 8 * (r >> 2) + 4 * half;
        int n = n0w + row;
        if (n < N) {
          int bi = bidx[n];
          float h = a[r] + bb;
          h = scale_eff[bi * 64 + c] * h + shift[bi * 64 + c];
          float z = h * s2v + o2v;
          out_bf[(size_t)n * 64 + c] = f2bf(silu_f(z));
        }
      }
    }
  } else {
#pragma unroll
    for (int cb = 0; cb < 2; ++cb) {
      f32x16 a = cb ? acc1 : acc0;
      int c = cb * 32 + r32;
      float bb = bias[c];
#pragma unroll
      for (int r = 0; r < 16; ++r) {
        int row = (r & 3) + 8 * (r >> 2) + 4 * half;
        int n = n0w + row;
        if (n < N) {
          out_f[(size_t)n * 64 + c] = a[r] + bb + xres[(size_t)n * 64 + c];
        }
      }
    }
  }
#undef LOADVG
#undef GATHER
#undef DO_MFMA
}

extern "C" void kernel_launch(void* const* d_in, const int* in_sizes, int n_in,
                              void* d_out, int out_size, void* d_ws, size_t ws_size,
                              hipStream_t stream) {
  const float* x    = (const float*)d_in[0];
  const float* t    = (const float*)d_in[1];
  const int*   b    = (const int*)d_in[2];
  const int*   kidx = (const int*)d_in[3];
  const int*   kval = (const int*)d_in[4];
  const float* bn1g = (const float*)d_in[5];
  const float* bn1b = (const float*)d_in[6];
  const float* bn1m = (const float*)d_in[7];
  const float* bn1v = (const float*)d_in[8];
  const float* W1   = (const float*)d_in[9];
  const float* b1c  = (const float*)d_in[10];
  const float* bn2g = (const float*)d_in[11];
  const float* bn2b = (const float*)d_in[12];
  const float* bn2m = (const float*)d_in[13];
  const float* bn2v = (const float*)d_in[14];
  const float* W2   = (const float*)d_in[15];
  const float* b2c  = (const float*)d_in[16];
  const float* Wt   = (const float*)d_in[17];
  const float* bt   = (const float*)d_in[18];
  float* out = (float*)d_out;

  const int N = in_sizes[2];        // 100000
  const int total = N * 64;

  // workspace layout (bytes)
  char* ws = (char*)d_ws;
  size_t actB = (size_t)total * 2;                 // 12.8 MB
  unsigned short* a1bf = (unsigned short*)ws;
  unsigned short* a2bf = (unsigned short*)(ws + actB);
  const size_t wpackB = (size_t)KOFF * 4 * 2 * 64 * 8 * 2;  // 221184 B
  unsigned short* W1p = (unsigned short*)(ws + 2 * actB);
  unsigned short* W2p = (unsigned short*)(ws + 2 * actB + wpackB);
  float* scale_eff = (float*)(ws + 2 * actB + 2 * wpackB);
  float* shiftp    = scale_eff + 16 * 64;
  float* s1 = shiftp + 16 * 64;
  float* o1 = s1 + 64;
  float* s2 = s1 + 128;
  float* o2 = s1 + 192;

  prep_bn<<<1, 64, 0, stream>>>(bn1g, bn1b, bn1m, bn1v, bn2g, bn2b, bn2m, bn2v,
                                s1, o1, s2, o2);
  time_mlp<<<8, 256, 0, stream>>>(t, Wt, bt, scale_eff, shiftp);
  pack_w32<<<(KOFF * 4 * 2 * 64 * 8 + 255) / 256, 256, 0, stream>>>(W1, W1p);
  pack_w32<<<(KOFF * 4 * 2 * 64 * 8 + 255) / 256, 256, 0, stream>>>(W2, W2p);
  bn_silu_k<<<(total / 4 + 255) / 256, 256, 0, stream>>>(x, s1, o1, a1bf, total);

  int nblk = (N + 127) / 128;
  conv_k<0><<<nblk, 256, 0, stream>>>(a1bf, kidx, kval, W1p, b1c, scale_eff,
                                      shiftp, b, s2, o2, nullptr, a2bf, nullptr, N);
  conv_k<1><<<nblk, 256, 0, stream>>>(a2bf, kidx, kval, W2p, b2c, nullptr, nullptr,
                                      nullptr, nullptr, nullptr, x, nullptr, out, N);
}